// Round 4
// baseline (123.663 us; speedup 1.0000x reference)
//
#include <hip/hip_runtime.h>

#define DIM   256
#define NQ    8
#define EMBED 512
#define FFN   2048
#define ROWS  (4 * 8192)             // B*S = 32768
#define OUT_VEC4  (EMBED / 4)        // 128 float4 per row
#define W_DIMS 32                    // embedding dims per column tile
#define CT_N   (EMBED / W_DIMS)      // 16 column tiles
#define R_ROWS 1024                  // rows per row tile
#define RT_N   (ROWS / R_ROWS)       // 32 row tiles
#define GRID   (CT_N * RT_N)         // 512 blocks

// Single kernel, no cross-block dependency.
// Block (ct, rt): computes z + full h redundantly (cheap, L2-served),
// then ov for its 32 dims only, then writes its 1024x32 output tile.
__global__ void __launch_bounds__(256)
k_fused(const float* __restrict__ U_re,
        const float* __restrict__ U_im,
        const float* __restrict__ W1,
        const float* __restrict__ b1,
        const float* __restrict__ W2,
        const float* __restrict__ b2,
        float* __restrict__ out) {
    int t  = threadIdx.x;
    int ct = blockIdx.x & (CT_N - 1);
    int rt = blockIdx.x >> 4;

    // ---- probs for basis state k = t:  psi = U[:,0] (stride DIM) ----
    float re = U_re[t * DIM];
    float im = U_im[t * DIM];
    float p  = re * re + im * im;

    // ---- z[q] = sum_k sign(bit(7-q) of k) * p[k], block reduction ----
    float zp[NQ];
#pragma unroll
    for (int q = 0; q < NQ; ++q)
        zp[q] = ((t >> (NQ - 1 - q)) & 1) ? -p : p;
#pragma unroll
    for (int off = 32; off > 0; off >>= 1) {
#pragma unroll
        for (int q = 0; q < NQ; ++q)
            zp[q] += __shfl_down(zp[q], off, 64);
    }
    __shared__ float zw[4][NQ];
    if ((t & 63) == 0) {
#pragma unroll
        for (int q = 0; q < NQ; ++q) zw[t >> 6][q] = zp[q];
    }
    __syncthreads();
    __shared__ float zs[NQ];
    if (t < NQ) zs[t] = zw[0][t] + zw[1][t] + zw[2][t] + zw[3][t];
    __syncthreads();

    float zr[NQ];
#pragma unroll
    for (int q = 0; q < NQ; ++q) zr[q] = zs[q];

    // ---- h = relu(W1 z + b1) into LDS (full 2048, 8 rows/thread) ----
    __shared__ float h[FFN];
#pragma unroll
    for (int r = 0; r < FFN / 256; ++r) {
        int f = r * 256 + t;
        const float4* w = (const float4*)(W1 + f * NQ);
        float4 w0 = w[0], w1 = w[1];
        float acc = b1[f];
        acc += zr[0] * w0.x + zr[1] * w0.y + zr[2] * w0.z + zr[3] * w0.w;
        acc += zr[4] * w1.x + zr[5] * w1.y + zr[6] * w1.z + zr[7] * w1.w;
        h[f] = fmaxf(acc, 0.f);
    }
    __syncthreads();

    // ---- ov for this block's 32 dims: wave w does dim p*4+w per pass ----
    __shared__ float ovs[W_DIMS];
    const float4* h4 = (const float4*)h;
    int wave = t >> 6, lane = t & 63;
#pragma unroll
    for (int pss = 0; pss < W_DIMS / 4; ++pss) {   // 8 passes x 4 waves
        int d = pss * 4 + wave;
        int e = ct * W_DIMS + d;
        const float4* row = (const float4*)(W2 + (size_t)e * FFN);
        float acc = 0.f;
#pragma unroll
        for (int j = 0; j < 8; ++j) {              // 64 lanes x 8 f4 = 512 f4
            float4 a = row[j * 64 + lane];
            float4 b = h4[j * 64 + lane];
            acc += a.x * b.x + a.y * b.y + a.z * b.z + a.w * b.w;
        }
#pragma unroll
        for (int off = 32; off > 0; off >>= 1)
            acc += __shfl_down(acc, off, 64);
        if (lane == 0) ovs[d] = acc + b2[e];
    }
    __syncthreads();

    // ---- write the 1024-row x 32-dim tile ----
    // thread t: float4 col c4 = t&7 (8 f4 cols), row slot rr = t>>3 (32 rows/iter)
    const float4* ovs4 = (const float4*)ovs;
    float4 v = ovs4[t & 7];
    float4* out4 = (float4*)out;
    int rr = t >> 3;
    size_t base = (size_t)rt * R_ROWS * OUT_VEC4 + ct * 8 + (t & 7);
#pragma unroll
    for (int i = 0; i < R_ROWS / 32; ++i)          // 32 stores/thread
        out4[base + (size_t)(rr + i * 32) * OUT_VEC4] = v;
}

extern "C" void kernel_launch(void* const* d_in, const int* in_sizes, int n_in,
                              void* d_out, int out_size, void* d_ws, size_t ws_size,
                              hipStream_t stream) {
    // inputs: x, U_re, U_im, W1, b1, W2, b2  (x is shape-only, unused)
    const float* U_re = (const float*)d_in[1];
    const float* U_im = (const float*)d_in[2];
    const float* W1   = (const float*)d_in[3];
    const float* b1   = (const float*)d_in[4];
    const float* W2   = (const float*)d_in[5];
    const float* b2   = (const float*)d_in[6];
    float* out = (float*)d_out;

    k_fused<<<GRID, 256, 0, stream>>>(U_re, U_im, W1, b1, W2, b2, out);
}

// Round 6
// 123.508 us; speedup vs baseline: 1.0013x; 1.0013x over previous
//
#include <hip/hip_runtime.h>

#define DIM   256
#define NQ    8
#define EMBED 512
#define FFN   2048
#define ROWS  (4 * 8192)             // B*S = 32768
#define OUT_ELEMS (ROWS * EMBED)     // 16777216 fp32
#define OUT_VEC4  (EMBED / 4)        // 128 float4 per row
#define OUT_TOTAL4 (OUT_ELEMS / 4)   // 4194304 float4
#define BC_GRID 4096                 // broadcast grid: 4096*256*4 stores = OUT_TOTAL4

typedef float vfloat4 __attribute__((ext_vector_type(4)));  // native vec for nt-store

// Kernel A: one block per output embedding e (512 blocks, 256 threads).
// Block redundantly computes z (from |U[:,0]|^2 marginals) and
// h = relu(W1 z + b1) (W1/U reads L2-hit after first block), then
// ov[e] = dot(W2[e,:], h) + b2[e]. W2 is read exactly once device-wide.
__global__ void __launch_bounds__(256)
k_ov(const float* __restrict__ U_re,
     const float* __restrict__ U_im,
     const float* __restrict__ W1,
     const float* __restrict__ b1,
     const float* __restrict__ W2,
     const float* __restrict__ b2,
     float* __restrict__ ov) {
    int t = threadIdx.x;
    int e = blockIdx.x;

    // ---- probs for basis state k = t ----
    float re = U_re[t * DIM];     // column 0, stride DIM
    float im = U_im[t * DIM];
    float p  = re * re + im * im;

    // ---- z[q] = sum_k sign(bit(7-q) of k) * p[k], block reduction ----
    float zp[NQ];
#pragma unroll
    for (int q = 0; q < NQ; ++q)
        zp[q] = ((t >> (NQ - 1 - q)) & 1) ? -p : p;
#pragma unroll
    for (int off = 32; off > 0; off >>= 1) {
#pragma unroll
        for (int q = 0; q < NQ; ++q)
            zp[q] += __shfl_down(zp[q], off, 64);
    }
    __shared__ float zw[4][NQ];
    if ((t & 63) == 0) {
#pragma unroll
        for (int q = 0; q < NQ; ++q) zw[t >> 6][q] = zp[q];
    }
    __syncthreads();
    __shared__ float zs[NQ];
    if (t < NQ) zs[t] = zw[0][t] + zw[1][t] + zw[2][t] + zw[3][t];
    __syncthreads();

    float zr[NQ];
#pragma unroll
    for (int q = 0; q < NQ; ++q) zr[q] = zs[q];

    // ---- h = relu(W1 z + b1) into LDS (8 rows/thread) ----
    __shared__ float h[FFN];
#pragma unroll
    for (int r = 0; r < FFN / 256; ++r) {
        int f = r * 256 + t;
        const float4* w = (const float4*)(W1 + f * NQ);  // 32B-aligned row
        float4 w0 = w[0], w1 = w[1];
        float acc = b1[f];
        acc += zr[0] * w0.x + zr[1] * w0.y + zr[2] * w0.z + zr[3] * w0.w;
        acc += zr[4] * w1.x + zr[5] * w1.y + zr[6] * w1.z + zr[7] * w1.w;
        h[f] = fmaxf(acc, 0.f);
    }
    __syncthreads();

    // ---- ov[e] = dot(W2[e,:], h) + b2[e] ----
    const float4* row = (const float4*)(W2 + (size_t)e * FFN);  // 8KB stride
    const float4* h4  = (const float4*)h;
    float4 a0 = row[t],       hb0 = h4[t];
    float4 a1 = row[256 + t], hb1 = h4[256 + t];
    float acc = a0.x * hb0.x + a0.y * hb0.y + a0.z * hb0.z + a0.w * hb0.w
              + a1.x * hb1.x + a1.y * hb1.y + a1.z * hb1.z + a1.w * hb1.w;
#pragma unroll
    for (int off = 32; off > 0; off >>= 1)
        acc += __shfl_down(acc, off, 64);
    __shared__ float wsum[4];
    if ((t & 63) == 0) wsum[t >> 6] = acc;
    __syncthreads();
    if (t == 0)
        ov[e] = wsum[0] + wsum[1] + wsum[2] + wsum[3] + b2[e];
}

// Kernel B: broadcast ov (512 floats) to all 32768 rows.
// stride = 4096*256 = 1048576 threads, % 128 == 0 -> each thread's float4
// column (idx & 127) is invariant: load ov once, 4 nontemporal stores,
// fully coalesced, exactly covering OUT_TOTAL4.
__global__ void __launch_bounds__(256)
k_broadcast(const float* __restrict__ ov,
            float* __restrict__ out) {
    const vfloat4* ov4 = (const vfloat4*)ov;
    vfloat4* out4 = (vfloat4*)out;
    int idx = blockIdx.x * blockDim.x + threadIdx.x;
    const int stride = BC_GRID * 256;          // 1048576, % 128 == 0
    vfloat4 v = ov4[idx & (OUT_VEC4 - 1)];
#pragma unroll
    for (int i = 0; i < OUT_TOTAL4 / (BC_GRID * 256); ++i)   // 4 stores
        __builtin_nontemporal_store(v, &out4[idx + i * stride]);
}

extern "C" void kernel_launch(void* const* d_in, const int* in_sizes, int n_in,
                              void* d_out, int out_size, void* d_ws, size_t ws_size,
                              hipStream_t stream) {
    // inputs: x, U_re, U_im, W1, b1, W2, b2  (x is shape-only, unused)
    const float* U_re = (const float*)d_in[1];
    const float* U_im = (const float*)d_in[2];
    const float* W1   = (const float*)d_in[3];
    const float* b1   = (const float*)d_in[4];
    const float* W2   = (const float*)d_in[5];
    const float* b2   = (const float*)d_in[6];
    float* out = (float*)d_out;

    float* ov = (float*)d_ws;    // 512 floats of scratch

    k_ov       <<<EMBED,   256, 0, stream>>>(U_re, U_im, W1, b1, W2, b2, ov);
    k_broadcast<<<BC_GRID, 256, 0, stream>>>(ov, out);
}

// Round 7
// 122.372 us; speedup vs baseline: 1.0105x; 1.0093x over previous
//
#include <hip/hip_runtime.h>

#define DIM   256
#define NQ    8
#define EMBED 512
#define FFN   2048
#define ROWS  (4 * 8192)             // B*S = 32768
#define OUT_ELEMS (ROWS * EMBED)     // 16777216 fp32
#define OUT_VEC4  (EMBED / 4)        // 128 float4 per row
#define OUT_TOTAL4 (OUT_ELEMS / 4)   // 4194304 float4
#define BC_GRID 4096                 // 4096*256 threads, stride % 128 == 0

// Kernel A: one block per output embedding e (512 blocks, 256 threads).
// Block redundantly computes z (from |U[:,0]|^2 marginals) and
// h = relu(W1 z + b1) (W1/U reads L2-hit after first block), then
// ov[e] = dot(W2[e,:], h) + b2[e]. W2 is read exactly once device-wide.
__global__ void __launch_bounds__(256)
k_ov(const float* __restrict__ U_re,
     const float* __restrict__ U_im,
     const float* __restrict__ W1,
     const float* __restrict__ b1,
     const float* __restrict__ W2,
     const float* __restrict__ b2,
     float* __restrict__ ov) {
    int t = threadIdx.x;
    int e = blockIdx.x;

    // ---- probs for basis state k = t ----
    float re = U_re[t * DIM];     // column 0, stride DIM
    float im = U_im[t * DIM];
    float p  = re * re + im * im;

    // ---- z[q] = sum_k sign(bit(7-q) of k) * p[k], block reduction ----
    float zp[NQ];
#pragma unroll
    for (int q = 0; q < NQ; ++q)
        zp[q] = ((t >> (NQ - 1 - q)) & 1) ? -p : p;
#pragma unroll
    for (int off = 32; off > 0; off >>= 1) {
#pragma unroll
        for (int q = 0; q < NQ; ++q)
            zp[q] += __shfl_down(zp[q], off, 64);
    }
    __shared__ float zw[4][NQ];
    if ((t & 63) == 0) {
#pragma unroll
        for (int q = 0; q < NQ; ++q) zw[t >> 6][q] = zp[q];
    }
    __syncthreads();
    __shared__ float zs[NQ];
    if (t < NQ) zs[t] = zw[0][t] + zw[1][t] + zw[2][t] + zw[3][t];
    __syncthreads();

    float zr[NQ];
#pragma unroll
    for (int q = 0; q < NQ; ++q) zr[q] = zs[q];

    // ---- h = relu(W1 z + b1) into LDS (8 rows/thread) ----
    __shared__ float h[FFN];
#pragma unroll
    for (int r = 0; r < FFN / 256; ++r) {
        int f = r * 256 + t;
        const float4* w = (const float4*)(W1 + f * NQ);  // 32B-aligned row
        float4 w0 = w[0], w1 = w[1];
        float acc = b1[f];
        acc += zr[0] * w0.x + zr[1] * w0.y + zr[2] * w0.z + zr[3] * w0.w;
        acc += zr[4] * w1.x + zr[5] * w1.y + zr[6] * w1.z + zr[7] * w1.w;
        h[f] = fmaxf(acc, 0.f);
    }
    __syncthreads();

    // ---- ov[e] = dot(W2[e,:], h) + b2[e] ----
    const float4* row = (const float4*)(W2 + (size_t)e * FFN);  // 8KB stride
    const float4* h4  = (const float4*)h;
    float4 a0 = row[t],       hb0 = h4[t];
    float4 a1 = row[256 + t], hb1 = h4[256 + t];
    float acc = a0.x * hb0.x + a0.y * hb0.y + a0.z * hb0.z + a0.w * hb0.w
              + a1.x * hb1.x + a1.y * hb1.y + a1.z * hb1.z + a1.w * hb1.w;
#pragma unroll
    for (int off = 32; off > 0; off >>= 1)
        acc += __shfl_down(acc, off, 64);
    __shared__ float wsum[4];
    if ((t & 63) == 0) wsum[t >> 6] = acc;
    __syncthreads();
    if (t == 0)
        ov[e] = wsum[0] + wsum[1] + wsum[2] + wsum[3] + b2[e];
}

// Kernel B: broadcast ov (512 floats) to all 32768 rows.
// stride = 4096*256 = 1048576 threads, % 128 == 0 -> each thread's float4
// column (idx & 127) is invariant: load ov once, store 4 float4s,
// fully coalesced.
__global__ void __launch_bounds__(256)
k_broadcast(const float* __restrict__ ov,
            float* __restrict__ out) {
    const float4* ov4 = (const float4*)ov;
    float4* out4 = (float4*)out;
    int idx = blockIdx.x * blockDim.x + threadIdx.x;
    const int stride = BC_GRID * 256;          // 1048576, % 128 == 0
    float4 v = ov4[idx & (OUT_VEC4 - 1)];
    for (; idx < OUT_TOTAL4; idx += stride)
        out4[idx] = v;
}

extern "C" void kernel_launch(void* const* d_in, const int* in_sizes, int n_in,
                              void* d_out, int out_size, void* d_ws, size_t ws_size,
                              hipStream_t stream) {
    // inputs: x, U_re, U_im, W1, b1, W2, b2  (x is shape-only, unused)
    const float* U_re = (const float*)d_in[1];
    const float* U_im = (const float*)d_in[2];
    const float* W1   = (const float*)d_in[3];
    const float* b1   = (const float*)d_in[4];
    const float* W2   = (const float*)d_in[5];
    const float* b2   = (const float*)d_in[6];
    float* out = (float*)d_out;

    float* ov = (float*)d_ws;    // 512 floats of scratch

    k_ov       <<<EMBED,   256, 0, stream>>>(U_re, U_im, W1, b1, W2, b2, ov);
    k_broadcast<<<BC_GRID, 256, 0, stream>>>(ov, out);
}